// Round 4
// baseline (205.088 us; speedup 1.0000x reference)
//
#include <hip/hip_runtime.h>

// mp: [1, 21, 16, 256, 256] fp32
#define CC   21
#define DD   16
#define HH   256
#define WW   256
#define HWP  (HH * WW)      // 65536
#define DHW  (DD * HWP)     // 1048576

typedef float f4a __attribute__((ext_vector_type(4), aligned(16)));
__device__ __forceinline__ f4a f4add(f4a a, f4a b) { return a + b; }

// ---------------------------------------------------------------------------
// FULLY FUSED: D-blur + H-blur (LDS) + W-blur + weighted-median in one kernel.
// No 176 MB intermediate round-trip. Block = (w:32, h:2, d-split:8 planes) x
// ALL 21 channels. LDS A[ch][dz][h][jj]: 21*8*2*36 = 48384 B -> 3 blocks/CU.
//
// Phase 1 (tid<189): task=(ch, jjq of 9). Loads 12 d-planes x 6 h-rows (72
// vec4), sliding 5-tap D-sum (verified associativity), ascending H-accum
// (verified), round-0 edge fixup post-blur (linear -> commutes bitwise).
// Phase 2 (tid<128): task=(wq,h,d). Two-pass median over c: pass1 tot,
// pass2 recompute v (bitwise-identical reads/adds) + cumsum flags, pass3
// stores. Exact verified arithmetic. LDS reads: each 8-lane group covers
// all 32 banks once (conflict-free, same structure as verified WH pass).
// ---------------------------------------------------------------------------
#define CH_STRIDE (8 * 2 * 36)       // 576 floats per channel
#define A_SZ      (CC * CH_STRIDE)   // 12096 floats = 48384 B

__global__ __launch_bounds__(256, 3) void fused_kernel(const float* __restrict__ mp,
                                                       float* __restrict__ out) {
    __shared__ float A[A_SZ];
    const int tid = threadIdx.x;

    // Bijective XCD-contiguous mapping: each XCD (idx&7) owns a contiguous
    // h-slab (16 ht = 32 rows) x all wt x s  -> halo re-reads hit its L2.
    const int idx = blockIdx.x;           // 0..2047
    const int o   = idx >> 3;             // 0..255
    const int ht  = (idx & 7) * 16 + (o & 15);   // 0..127
    const int wt  = (o >> 4) & 7;         // 0..7
    const int s   = o >> 7;               // 0..1 (d-planes s*8 .. s*8+7)
    const int w0  = wt * 32;
    const int h0  = ht * 2;

    // ---- phase 1: stage DH-blurred tile for all channels ----
    if (tid < 189) {
        const int ch  = tid / 9;
        const int jjq = tid - ch * 9;             // jj = jjq*4 .. jjq*4+3
        int lw = w0 - 2 + jjq * 4;
        const bool lo = (lw < 0);                 // wt==0, jjq==0
        const bool hi = (lw > WW - 4);            // wt==7, jjq==8
        lw = lo ? 0 : (hi ? (WW - 4) : lw);
        const float* __restrict__ src = mp + (size_t)ch * DHW + lw;

        f4a ha[8], hb[8];                         // H-accumulators, h0 and h0+1
#pragma unroll
        for (int r = 0; r < 6; ++r) {
            const int hh = min(HH - 1, max(0, h0 + r - 2));
            const float* rowp = src + (size_t)hh * WW;
            f4a l[12];
#pragma unroll
            for (int m = 0; m < 12; ++m) {
                const int dz = s * 8 + m;                   // staged plane
                const int d  = min(DD - 1, max(0, dz - 2)); // replicate clamp in D
                l[m] = *(const f4a*)(rowp + (size_t)d * HWP);
            }
            // verified sliding D-sum
            f4a sum = f4add(f4add(f4add(l[0], l[1]), f4add(l[2], l[3])), l[4]);
#pragma unroll
            for (int i = 0; i < 8; ++i) {
                // verified ascending H accumulation:
                // ha = ((((r0+r1)+r2)+r3)+r4 ; hb = ((((r1+r2)+r3)+r4)+r5
                if (r == 0)      ha[i] = sum;
                else if (r < 5)  ha[i] = f4add(ha[i], sum);
                if (r == 1)      hb[i] = sum;
                else if (r > 1)  hb[i] = f4add(hb[i], sum);
                if (i < 7) sum = sum - l[i] + l[i + 5];
            }
        }
#pragma unroll
        for (int i = 0; i < 8; ++i) {
            f4a oa = ha[i], ob = hb[i];
            // round-0 verified w-replicate fixup (post-blur; linear -> commutes):
            if (lo) { oa = f4a{oa.x, oa.x, oa.x, oa.y}; ob = f4a{ob.x, ob.x, ob.x, ob.y}; }
            if (hi) { oa = f4a{oa.z, oa.w, oa.w, oa.w}; ob = f4a{ob.z, ob.w, ob.w, ob.w}; }
            float* ap = &A[ch * CH_STRIDE + i * 72 + jjq * 4];
            *(f4a*)(ap)      = oa;   // h = h0
            *(f4a*)(ap + 36) = ob;   // h = h0+1
        }
    }
    __syncthreads();

    // ---- phase 2: W-blur + weighted median + store (tid<128) ----
    if (tid < 128) {
        const int wq = tid & 7;          // w-quad 0..7
        const int h  = (tid >> 3) & 1;   // 0..1
        const int d  = tid >> 4;         // 0..7
        const float* __restrict__ base = &A[d * 72 + h * 36 + wq * 4];

        // pass 1: tot (verified: ascending c, left-assoc W sums)
        float tot[4] = {0.f, 0.f, 0.f, 0.f};
#pragma unroll
        for (int c = 0; c < CC; ++c) {
            const f4a a0 = *(const f4a*)(base + c * CH_STRIDE);
            const f4a a1 = *(const f4a*)(base + c * CH_STRIDE + 4);
            tot[0] += ((((a0.x + a0.y) + a0.z) + a0.w) + a1.x);
            tot[1] += ((((a0.y + a0.z) + a0.w) + a1.x) + a1.y);
            tot[2] += ((((a0.z + a0.w) + a1.x) + a1.y) + a1.z);
            tot[3] += ((((a0.w + a1.x) + a1.y) + a1.z) + a1.w);
        }
        float inv[4];
#pragma unroll
        for (int p = 0; p < 4; ++p) inv[p] = 1.0f / tot[p];

        // pass 2: recompute v bitwise-identically, run verified median scan
        float sa[4] = {0.f, 0.f, 0.f, 0.f};
        float v0[4], v1[4];
        int m0[4] = {0, 0, 0, 0}, m1[4] = {0, 0, 0, 0};
#pragma unroll
        for (int c = 0; c < CC; ++c) {
            const f4a a0 = *(const f4a*)(base + c * CH_STRIDE);
            const f4a a1 = *(const f4a*)(base + c * CH_STRIDE + 4);
            float v[4];
            v[0] = ((((a0.x + a0.y) + a0.z) + a0.w) + a1.x);
            v[1] = ((((a0.y + a0.z) + a0.w) + a1.x) + a1.y);
            v[2] = ((((a0.z + a0.w) + a1.x) + a1.y) + a1.z);
            v[3] = ((((a0.w + a1.x) + a1.y) + a1.z) + a1.w);
#pragma unroll
            for (int p = 0; p < 4; ++p) {
                const float yn = v[p] * inv[p];
                const float sn = sa[p] + yn;
                if (c == 0) { v0[p] = yn; v1[p] = yn; }                           // defaults
                if (v[p] > 0.f && sn < 0.5f) { m0[p] = c; v0[p] = yn; }           // last qualifying
                if (m1[p] == 0 && c > 0 && sn > 0.5f) { m1[p] = c; v1[p] = yn; }  // first qualifying
                sa[p] = sn;
            }
        }

        // pass 3: stores (only m0/m1 channels nonzero)
        float* __restrict__ dst = out + (size_t)(s * 8 + d) * HWP
                                + (size_t)(h0 + h) * WW + w0 + wq * 4;
#pragma unroll
        for (int c = 0; c < CC; ++c) {
            f4a ov;
            ov.x = (c == m0[0]) ? v0[0] : ((c == m1[0]) ? v1[0] : 0.f);
            ov.y = (c == m0[1]) ? v0[1] : ((c == m1[1]) ? v1[1] : 0.f);
            ov.z = (c == m0[2]) ? v0[2] : ((c == m1[2]) ? v1[2] : 0.f);
            ov.w = (c == m0[3]) ? v0[3] : ((c == m1[3]) ? v1[3] : 0.f);
            *(f4a*)(dst + (size_t)c * DHW) = ov;
        }
    }
}

extern "C" void kernel_launch(void* const* d_in, const int* in_sizes, int n_in,
                              void* d_out, int out_size, void* d_ws, size_t ws_size,
                              hipStream_t stream) {
    const float* mp = (const float*)d_in[0];
    float* out = (float*)d_out;

    // 8 wt x 128 ht x 2 s = 2048 blocks (XCD-swizzled inside the kernel)
    fused_kernel<<<2048, 256, 0, stream>>>(mp, out);
}

// Round 5
// 185.761 us; speedup vs baseline: 1.1040x; 1.1040x over previous
//
#include <hip/hip_runtime.h>

// mp: [1, 21, 16, 256, 256] fp32
#define CC   21
#define DD   16
#define HH   256
#define WW   256
#define HWP  (HH * WW)      // 65536
#define DHW  (DD * HWP)     // 1048576

typedef float f4a __attribute__((ext_vector_type(4), aligned(16)));
__device__ __forceinline__ f4a f4add(f4a a, f4a b) { return a + b; }

// ---------------------------------------------------------------------------
// K1: D-blur (registers) + H-blur (LDS). Traffic-minimized: one column task
// (py,x4) loads ALL 16 distinct d-planes once (was: two s-splits x 12 loads
// = 24 plane-rows, 1.5x redundancy) and runs BOTH verified s-chains via
// compile-time re-indexing into P[16] -> bitwise-identical arithmetic,
// 132 MB reads instead of 198 MB. A layout / H-pass verbatim from the
// verified round-1 kernel. Blocks XCD-chunked with yb fastest so the 4-row
// h-halo re-read hits the same XCD's L2.
// ---------------------------------------------------------------------------
#define AROW 36
#define PYN  12
#define A_SZ (DD * PYN * AROW)   // 27648 B -> 5 blocks/CU

#define NB1  (8 * 32 * CC)       // 5376 blocks
#define CHK1 (NB1 / 8)           // 672 per XCD (5376 % 8 == 0 -> bijective)

__global__ __launch_bounds__(256, 5) void dh_blur_kernel(const float* __restrict__ mp,
                                                         float* __restrict__ out) {
    __shared__ float A[A_SZ];
    const int tid = threadIdx.x;

    // bijective XCD-chunked order, yb fastest within a chunk
    const int bid = blockIdx.x;
    const int t   = (bid & 7) * CHK1 + (bid >> 3);
    const int yb  = t & 31;
    const int wt  = (t >> 5) & 7;
    const int ch  = t >> 8;
    const int w0  = wt * 32;
    const int h0  = yb * 8;

    // ---- stage: 96 column tasks, 16 loads each, both verified D-chains ----
    if (tid < 96) {
        const int py = tid >> 3;             // 0..11
        const int x4 = tid & 7;              // quad 0..7
        const int h  = min(HH - 1, max(0, h0 + py - 2));
        const float* colp = mp + (size_t)ch * DHW + (size_t)h * WW + w0 + x4 * 4;

        f4a P[16];
#pragma unroll
        for (int d = 0; d < 16; ++d) P[d] = *(const f4a*)(colp + (size_t)d * HWP);

        // verified round-1 chains, re-indexed into P:
        // s=0: l[m] = P[clamp(m-2)]   -> {0,0,0,1,2,3,4,5,6,7,8,9}
        // s=1: l[m] = P[clamp(6+m)]   -> {6,7,8,9,10,11,12,13,14,15,15,15}
        constexpr int M0[12] = {0, 0, 0, 1, 2, 3, 4, 5, 6, 7, 8, 9};
        constexpr int M1[12] = {6, 7, 8, 9, 10, 11, 12, 13, 14, 15, 15, 15};

        {   // s = 0: output planes 0..7
            f4a sum = f4add(f4add(f4add(P[M0[0]], P[M0[1]]),
                                  f4add(P[M0[2]], P[M0[3]])), P[M0[4]]);
#pragma unroll
            for (int i = 0; i < 8; ++i) {
                *(f4a*)(&A[(i * PYN + py) * AROW + x4 * 4]) = sum;
                if (i < 7) sum = sum - P[M0[i]] + P[M0[i + 5]];
            }
        }
        {   // s = 1: output planes 8..15
            f4a sum = f4add(f4add(f4add(P[M1[0]], P[M1[1]]),
                                  f4add(P[M1[2]], P[M1[3]])), P[M1[4]]);
#pragma unroll
            for (int i = 0; i < 8; ++i) {
                *(f4a*)(&A[((8 + i) * PYN + py) * AROW + x4 * 4]) = sum;
                if (i < 7) sum = sum - P[M1[i]] + P[M1[i + 5]];
            }
        }
    }
    __syncthreads();

    // ---- H pass: verbatim verified round-1 code ----
#pragma unroll
    for (int it = 0; it < 4; ++it) {
        const int tt   = tid + it * 256;
        const int xx4  = tt & 7;
        const int y    = (tt >> 3) & 7;
        const int dout = tt >> 6;

        const float* b = &A[(dout * PYN + y) * AROW + xx4 * 4];
        f4a a = *(const f4a*)b;
#pragma unroll
        for (int k = 1; k < 5; ++k) a = f4add(a, *(const f4a*)(b + k * AROW));

        *(f4a*)(out + (size_t)ch * DHW + (size_t)dout * HWP
                + (h0 + y) * WW + w0 + xx4 * 4) = a;
    }
}

// ---------------------------------------------------------------------------
// K2: W-blur + weighted-median, verbatim verified round-1 kernel.
// Block = one (d,h) row, all 21 channels staged in LDS (22.2 KB -> 7/CU).
// In-place safe: a row is read and overwritten only by its own block.
// ---------------------------------------------------------------------------
#define ROWP 264   // 2 pad + 2 lo-edge + 256 data + 2 hi-edge + 2 pad

__global__ __launch_bounds__(256) void wmedian_kernel(float* __restrict__ y4) {
    __shared__ float R[CC * ROWP];

    const int h = blockIdx.x;
    const int d = blockIdx.y;
    const int tid = threadIdx.x;
    float* __restrict__ base = y4 + (size_t)d * HWP + (size_t)h * WW;

    // stage: 21 rows x 64 aligned float4
    for (int idx = tid; idx < CC * 64; idx += 256) {
        const int c  = idx >> 6;
        const int w4 = idx & 63;
        *(f4a*)(&R[c * ROWP + 4 + w4 * 4]) = *(const f4a*)(base + (size_t)c * DHW + w4 * 4);
    }
    // replicate edges
    if (tid < CC) {
        const float v0 = base[(size_t)tid * DHW];
        const float vL = base[(size_t)tid * DHW + (WW - 1)];
        R[tid * ROWP + 2]   = v0;
        R[tid * ROWP + 3]   = v0;
        R[tid * ROWP + 260] = vL;
        R[tid * ROWP + 261] = vL;
    }
    __syncthreads();

    const int w = tid;   // 0..255
    float v[CC];
    float tot = 0.f;
#pragma unroll
    for (int c = 0; c < CC; ++c) {
        const float* r = &R[c * ROWP + 2 + w];           // r[0] = value at w-2
        v[c] = ((((r[0] + r[1]) + r[2]) + r[3]) + r[4]); // verified W order
        tot += v[c];
    }
    const float inv = 1.0f / tot;

    float s = 0.f, sv0 = 0.f, sv1 = 0.f;
    int m0 = 0, m1 = 0;
#pragma unroll
    for (int c = 0; c < CC; ++c) {
        const float yn = v[c] * inv;
        const float sn = s + yn;
        if (c == 0) { sv0 = yn; sv1 = yn; }                           // defaults
        if (v[c] > 0.f && sn < 0.5f) { m0 = c; sv0 = yn; }            // last qualifying
        if (m1 == 0 && c > 0 && sn > 0.5f) { m1 = c; sv1 = yn; }      // first qualifying
        s = sn;
    }

#pragma unroll
    for (int c = 0; c < CC; ++c) {
        base[(size_t)c * DHW + w] = (c == m0) ? sv0 : ((c == m1) ? sv1 : 0.f);
    }
}

extern "C" void kernel_launch(void* const* d_in, const int* in_sizes, int n_in,
                              void* d_out, int out_size, void* d_ws, size_t ws_size,
                              hipStream_t stream) {
    const float* mp = (const float*)d_in[0];
    float* out = (float*)d_out;

    dh_blur_kernel<<<NB1, 256, 0, stream>>>(mp, out);       // 5376 blocks, XCD-chunked
    wmedian_kernel<<<dim3(HH, DD), 256, 0, stream>>>(out);  // 4096 blocks
}